// Round 1
// baseline (647.026 us; speedup 1.0000x reference)
//
#include <hip/hip_runtime.h>
#include <math.h>

#define T_DIM 2048
#define N_DIM 64
#define D_DIM 1024
#define TC    32                    // t's per wave
#define CHUNKS (T_DIM / TC)         // 64 chunks over T
#define EPS 1e-6f
#define HALF_LOG_2PI 0.91893853320467274178f

__global__ void zero_out_kernel(float* out) {
    out[threadIdx.x] = 0.0f;
}

// One wave (64 lanes) handles one sequence n for TC consecutive t's.
// Row x[t,n,:] is 1024 floats = 4KB; lane i loads float4 index j*64+i
// (j=0..3) -> each load instruction is a contiguous, aligned 1KB segment.
__global__ __launch_bounds__(256) void gnll_kernel(
    const float* __restrict__ y,    // (T, N)
    const float* __restrict__ x,    // (T, N, D)
    const float* __restrict__ W,    // (2, D)
    const int*   __restrict__ lens, // (N)
    float*       __restrict__ out)  // (N)
{
    const int lane = threadIdx.x & 63;
    const int wave = threadIdx.x >> 6;
    const int wg   = blockIdx.x * 4 + wave;     // global wave id
    const int n     = wg & (N_DIM - 1);         // consecutive waves -> consecutive n (contiguous rows)
    const int chunk = wg >> 6;                  // which t-chunk
    const int len = lens[n];
    const int t0 = chunk * TC;
    if (t0 >= len) return;                      // skip masked work entirely (saves ~half of HBM reads)
    const int t1 = min(t0 + TC, len);

    // Preload W fragments: lane covers float4 indices j*64+lane of each row.
    const float4* W0 = (const float4*)W;
    const float4* W1 = (const float4*)(W + D_DIM);
    float4 w0[4], w1[4];
#pragma unroll
    for (int j = 0; j < 4; ++j) {
        w0[j] = W0[j * 64 + lane];
        w1[j] = W1[j * 64 + lane];
    }

    float acc = 0.0f;
    for (int t = t0; t < t1; ++t) {
        const float4* xr = (const float4*)(x + ((size_t)t * N_DIM + n) * D_DIM);
        float m = 0.0f, s = 0.0f;
#pragma unroll
        for (int j = 0; j < 4; ++j) {
            float4 xv = xr[j * 64 + lane];
            m += xv.x * w0[j].x + xv.y * w0[j].y + xv.z * w0[j].z + xv.w * w0[j].w;
            s += xv.x * w1[j].x + xv.y * w1[j].y + xv.z * w1[j].z + xv.w * w1[j].w;
        }
        // Butterfly reduce both dot products across the 64-lane wave.
#pragma unroll
        for (int off = 32; off > 0; off >>= 1) {
            m += __shfl_xor(m, off, 64);
            s += __shfl_xor(s, off, 64);
        }
        const float yv   = y[(size_t)t * N_DIM + n];
        const float sg   = 1.0f / (1.0f + __expf(-s));
        const float var  = fmaxf(sg, EPS);
        const float diff = yv - m;
        const float nll  = 0.5f * (__logf(var) + diff * diff / var) + HALF_LOG_2PI;
        if (lane == 0) acc += nll;
    }
    if (lane == 0) atomicAdd(out + n, acc);
}

extern "C" void kernel_launch(void* const* d_in, const int* in_sizes, int n_in,
                              void* d_out, int out_size, void* d_ws, size_t ws_size,
                              hipStream_t stream) {
    const float* y    = (const float*)d_in[0];
    const float* x    = (const float*)d_in[1];
    const float* W    = (const float*)d_in[2];
    const int*   lens = (const int*)d_in[3];
    float* out = (float*)d_out;

    zero_out_kernel<<<1, N_DIM, 0, stream>>>(out);
    // N_DIM * CHUNKS waves / 4 waves-per-block = 1024 blocks
    gnll_kernel<<<(N_DIM * CHUNKS) / 4, 256, 0, stream>>>(y, x, W, lens, out);
}

// Round 2
// 640.176 us; speedup vs baseline: 1.0107x; 1.0107x over previous
//
#include <hip/hip_runtime.h>
#include <math.h>

#define T_DIM 2048
#define N_DIM 64
#define D_DIM 1024
#define TC    16                    // t's per wave
#define CHUNKS (T_DIM / TC)         // 128 chunks over T
#define EPS 1e-6f
#define HALF_LOG_2PI 0.91893853320467274178f

__global__ void zero_out_kernel(float* out) {
    out[threadIdx.x] = 0.0f;
}

// One wave handles sequence n, t in [chunk*TC, chunk*TC+TC).
// 2 rows per iteration: lanes 0-31 own row t, lanes 32-63 own row t+1.
// Each half-wave covers the 1024-float row as 8 float4 per lane
// (lane c loads float4 index j*32+c, j=0..7 -> 512B contiguous per half
// per instruction). Reduce = 5 xor-steps within 32-lane halves.
__global__ __launch_bounds__(256) void gnll_kernel(
    const float* __restrict__ y,    // (T, N)
    const float* __restrict__ x,    // (T, N, D)
    const float* __restrict__ W,    // (2, D)
    const int*   __restrict__ lens, // (N)
    float*       __restrict__ out)  // (N)
{
    const int lane = threadIdx.x & 63;
    const int wave = threadIdx.x >> 6;
    const int wg   = blockIdx.x * 4 + wave;     // global wave id
    const int n     = wg & (N_DIM - 1);         // consecutive waves -> consecutive n
    const int chunk = wg >> 6;                  // which t-chunk
    const int len = lens[n];
    const int t0 = chunk * TC;
    if (t0 >= len) return;                      // skip masked chunks: ~half of HBM reads saved
    const int t1 = min(t0 + TC, len);

    const int half = lane >> 5;                 // which of the 2 rows this lane works on
    const int c    = lane & 31;                 // float4 slot within the row

    // Preload W fragments for this lane's row positions (hot in L1 across all waves).
    const float4* W0 = (const float4*)W;
    const float4* W1 = (const float4*)(W + D_DIM);
    float4 w0[8], w1[8];
#pragma unroll
    for (int j = 0; j < 8; ++j) {
        w0[j] = W0[j * 32 + c];
        w1[j] = W1[j * 32 + c];
    }

    float acc = 0.0f;
    for (int t2 = t0; t2 < t1; t2 += 2) {
        const int t = t2 + half;                // lanes 32-63 take the odd row
        const float4* xr = (const float4*)(x + ((size_t)t * N_DIM + n) * D_DIM) + c;
        float m = 0.0f, s = 0.0f;
#pragma unroll
        for (int j = 0; j < 8; ++j) {
            float4 xv = xr[j * 32];
            m += xv.x * w0[j].x + xv.y * w0[j].y + xv.z * w0[j].z + xv.w * w0[j].w;
            s += xv.x * w1[j].x + xv.y * w1[j].y + xv.z * w1[j].z + xv.w * w1[j].w;
        }
        // Reduce both dot products within each 32-lane half (5 steps).
#pragma unroll
        for (int off = 16; off > 0; off >>= 1) {
            m += __shfl_xor(m, off, 64);
            s += __shfl_xor(s, off, 64);
        }
        // Each half now holds its own row's (m, s); compute nll for 2 rows at once.
        const float yv   = y[(size_t)t * N_DIM + n];
        const float sg   = 1.0f / (1.0f + __expf(-s));
        const float var  = fmaxf(sg, EPS);
        const float diff = yv - m;
        const float nll  = 0.5f * (__logf(var) + diff * diff / var) + HALF_LOG_2PI;
        const bool valid = (t < len) && (c == 0);
        acc += valid ? nll : 0.0f;              // predicated, no divergence
    }
    // Combine the two halves' accumulators (lanes 0 and 32 hold data).
    acc += __shfl_xor(acc, 32, 64);
    if (lane == 0) atomicAdd(out + n, acc);
}

extern "C" void kernel_launch(void* const* d_in, const int* in_sizes, int n_in,
                              void* d_out, int out_size, void* d_ws, size_t ws_size,
                              hipStream_t stream) {
    const float* y    = (const float*)d_in[0];
    const float* x    = (const float*)d_in[1];
    const float* W    = (const float*)d_in[2];
    const int*   lens = (const int*)d_in[3];
    float* out = (float*)d_out;

    zero_out_kernel<<<1, N_DIM, 0, stream>>>(out);
    // N_DIM * CHUNKS waves / 4 waves-per-block = 2048 blocks
    gnll_kernel<<<(N_DIM * CHUNKS) / 4, 256, 0, stream>>>(y, x, W, lens, out);
}